// Round 11
// baseline (3129.831 us; speedup 1.0000x reference)
//
#include <hip/hip_runtime.h>

#define T_STEPS 1000
#define N_IN    700
#define N_HID   4096
#define N_OUT   20
#define NBLK    256   // main-loop blocks: 1 wave, 16 neurons each
#define NPB     16    // neurons per block

typedef unsigned int u32x4 __attribute__((ext_vector_type(4)));
typedef unsigned int u32x2 __attribute__((ext_vector_type(2)));

// device-coherent record ops; waitcnt INSIDE asm (no live in-flight regs)
__device__ __forceinline__ u32x4 load_rec_syncx4(const u32x4* p) {
    u32x4 r;
    asm volatile("global_load_dwordx4 %0, %1, off sc0 sc1\n\t"
                 "s_waitcnt vmcnt(0)"
                 : "=v"(r) : "v"(p) : "memory");
    return r;
}
__device__ __forceinline__ void store_rec4(unsigned* p, unsigned v) {
    asm volatile("global_store_dword %0, %1, off sc0 sc1"
                 :: "v"(p), "v"(v) : "memory");
}

// ---------------------------------------------------------------------------
// w1t[c*4096 + r] = (int8) w1[r*700 + c]
__global__ __launch_bounds__(256) void k_transpose_i8(
    const int* __restrict__ in, signed char* __restrict__ out,
    int R, int C, int out_stride)
{
    __shared__ signed char tile[32][33];
    const int cx = blockIdx.x * 32;
    const int ry = blockIdx.y * 32;
    const int tx = threadIdx.x;
    const int ty = threadIdx.y;
#pragma unroll
    for (int r = 0; r < 4; ++r) {
        int row = ry + ty + r * 8;
        int col = cx + tx;
        if (row < R && col < C)
            tile[ty + r * 8][tx] = (signed char)in[(size_t)row * C + col];
    }
    __syncthreads();
#pragma unroll
    for (int r = 0; r < 4; ++r) {
        int c   = cx + ty + r * 8;
        int row = ry + tx;
        if (c < C && row < R)
            out[(size_t)c * out_stride + row] = tile[tx][ty + r * 8];
    }
}

// ---------------------------------------------------------------------------
// v1n[b][k] = 8B row: 16 nibbles = (v1[b*16+j][k] + 8), j=0..15
__global__ __launch_bounds__(256) void k_prep_v1n(
    const int* __restrict__ in, unsigned char* __restrict__ out)
{
    __shared__ unsigned char tile[16][64];
    const int k0 = blockIdx.x * 64;
    const int b  = blockIdx.y;
    const int t  = threadIdx.x;
    const int kk = t & 63;
#pragma unroll
    for (int r = 0; r < 4; ++r) {
        int hl = (t >> 6) + r * 4;     // 0..15
        tile[hl][kk] = (unsigned char)(in[(size_t)(b * NPB + hl) * N_HID + k0 + kk] + 8);
    }
    __syncthreads();
    if (t < 64) {
        unsigned w0 = 0, w1 = 0;
#pragma unroll
        for (int j = 0; j < 8; ++j) w0 |= (unsigned)tile[j][t] << (4 * j);
#pragma unroll
        for (int j = 0; j < 8; ++j) w1 |= (unsigned)tile[8 + j][t] << (4 * j);
        u32x2 v = {w0, w1};
        *(u32x2*)(out + ((size_t)b << 15) + ((size_t)(k0 + t) << 3)) = v;
    }
}

// ---------------------------------------------------------------------------
// in_all2 pair-interleaved: short idx = b*16000 + (t>>1)*32 + j*2 + (t&1)
// so (in(2I,j), in(2I+1,j)) form one aligned dword.
__global__ __launch_bounds__(256) void k_inall(
    const signed char* __restrict__ w1t,   // [N_IN][N_HID]
    const int* __restrict__ spk,           // [T][N_IN]
    short* __restrict__ in_all2)
{
    __shared__ int s_spk[16][N_IN];
    const int t0 = blockIdx.y * 16;
    const int tcnt = min(16, T_STEPS - t0);
    const int tid = threadIdx.x;
    for (int b = 0; b < tcnt; ++b)
        for (int i = tid; i < N_IN; i += 256)
            s_spk[b][i] = spk[(size_t)(t0 + b) * N_IN + i];
    __syncthreads();
    const int h = blockIdx.x * 256 + tid;
    int acc[16];
#pragma unroll
    for (int b = 0; b < 16; ++b) acc[b] = 0;
    for (int i = 0; i < N_IN; ++i) {
        int w = (int)w1t[(size_t)i * N_HID + h];
#pragma unroll
        for (int b = 0; b < 16; ++b) acc[b] += w * s_spk[b][i];
    }
    const size_t base = (size_t)(h >> 4) * (T_STEPS * NPB) + (size_t)(h & 15) * 2;
    for (int b = 0; b < tcnt; ++b) {
        int t = t0 + b;
        in_all2[base + (size_t)(t >> 1) * 32 + (t & 1)] = (short)acc[b];
    }
}

// ---------------------------------------------------------------------------
// Main LIF loop, TWO timesteps per iteration with loop rotation.
// Iter I processes t=2I, 2I+1. Masks for both gathers (rows 2I-1, 2I) are
// known at entry (prefetched via global_load_lds last iter). The B-side
// butterfly + syn update + thr/publish of pub[2I+1] are ROTATED to the top
// of iter I (register-only, hides the prefetch drain). pub[2I+2] publishes
// mid-iter after gather A. Straggler fallback: one dwordx4 sync retry.
__global__ __launch_bounds__(64) void k_main(
    const short* __restrict__ in_all2,      // pair-interleaved
    const u32x2* __restrict__ v1n,          // [256][4096] 8B nibble rows
    unsigned* __restrict__ pub)             // [T+4][256], flags zeroed
{
    const int lane = threadIdx.x;
    const int bid  = blockIdx.x;
    const int j    = lane & 15;             // mirrored neuron index

    __shared__ u32x2 s_w[N_HID + 1];        // 32KB weight slice + zero row
    __shared__ u32x4 s_recA[2][64];         // rows 2I-1 (dbuf)
    __shared__ u32x4 s_recB[2][64];         // rows 2I   (dbuf)

    {   // load weight slice once
        const u32x2* src = v1n + ((size_t)bid << 12);
        for (int r = lane; r < N_HID; r += 64) s_w[r] = src[r];
        if (lane == 0) { u32x2 z = {0u, 0u}; s_w[N_HID] = z; }
    }
    asm volatile("s_waitcnt vmcnt(0) lgkmcnt(0)" ::: "memory");

    if (lane == 0) store_rec4(pub + bid, 0x10000u);   // pub[0]: out(0)=0

    const u32x2* wl = s_w + (lane << 6);
    const int bz = N_HID - (lane << 6);     // per-lane index of the zero row
    const unsigned M4 = 0x0F0F0F0Fu, M8 = 0x00FF00FFu;
    const int j0 = j & 1, j1 = j & 2, j3 = j & 8;
    const int jsh = (j & 4) << 2;
    const int* ip_base = (const int*)in_all2 + (size_t)bid * 8000 + j;

#define BFLY_FIELD(a0,a1,a2,a3,a4,a5,a6,a7,gout) do {                      \
        unsigned e0 = (j0 ? a2 : a0) + __shfl_xor(j0 ? a0 : a2, 1);        \
        unsigned e1 = (j0 ? a3 : a1) + __shfl_xor(j0 ? a1 : a3, 1);        \
        unsigned e2 = (j0 ? a6 : a4) + __shfl_xor(j0 ? a4 : a6, 1);        \
        unsigned e3 = (j0 ? a7 : a5) + __shfl_xor(j0 ? a5 : a7, 1);        \
        unsigned f0 = (j1 ? e1 : e0) + __shfl_xor(j1 ? e0 : e1, 2);        \
        unsigned f1 = (j1 ? e3 : e2) + __shfl_xor(j1 ? e2 : e3, 2);        \
        unsigned g  = (j3 ? f1 : f0) + __shfl_xor(j3 ? f0 : f1, 8);        \
        g += __shfl_xor(g, 4); g += __shfl_xor(g, 16); g += __shfl_xor(g, 32); \
        gout = g; } while (0)

    // rotated/loop-carried state (iter-0 entry = all-zero history)
    int syn_m2 = 0;          // syn(2I-2)
    int in1_prev = 0;        // in(2I-1)
    int mpr = 0;             // m'(2I)
    int out_c = 0;           // out(2I)
    int nBred = 0;           // reduced count of row 2I-2
    unsigned bB0=0,bB1=0,bB2=0,bB3=0,bB4=0,bB5=0,bB6=0,bB7=0;  // acc(row 2I-2)
    int ip_cur = ip_base[0]; // (in(0), in(1))

    for (int I = 0; I < T_STEPS / 2; ++I) {
        const int cur = I & 1;

        // ===== step 0 (rotated): fb(2I-1), syn(2I-1), out(2I+1) =====
        unsigned gBf;
        BFLY_FIELD(bB0,bB1,bB2,bB3,bB4,bB5,bB6,bB7,gBf);
        int fbB = (int)((gBf >> jsh) & 0xFFFFu) - 8 * nBred;
        int syn_m1 = (syn_m2 - (syn_m2 >> 4)) + in1_prev + fbB;  // syn(2I-1)
        int memv = (mpr - (mpr >> 3)) + syn_m1;                  // new_mem(2I)
        int mpr1 = out_c ? 0 : memv;                             // m'(2I+1)
        int out1 = (mpr1 - 1 > 0) ? 1 : 0;                       // out(2I+1)
        unsigned om1 = (unsigned)__ballot(out1) & 0xFFFFu;

        // ===== drain prev iter's prefetches/loads =====
        asm volatile("s_waitcnt vmcnt(0)" ::: "memory");
        __builtin_amdgcn_sched_barrier(0);

        if (lane == 0)
            store_rec4(pub + (size_t)(2 * I + 1) * NBLK + bid, 0x10000u | om1);

        // ===== masks: rows 2I-1 (A), 2I (B) =====
        unsigned mAlo = 0, mAhi = 0, mBlo = 0, mBhi = 0;
        if (I > 0) {
            u32x4 qA = s_recA[cur][lane];
            if (((qA.x & qA.y & qA.z & qA.w) & 0x10000u) == 0u) {
                const u32x4* rp = (const u32x4*)(pub + (size_t)(2 * I - 1) * NBLK) + lane;
                do { __builtin_amdgcn_s_sleep(1); qA = load_rec_syncx4(rp); }
                while (((qA.x & qA.y & qA.z & qA.w) & 0x10000u) == 0u);
            }
            u32x4 qB = s_recB[cur][lane];
            if (((qB.x & qB.y & qB.z & qB.w) & 0x10000u) == 0u) {
                const u32x4* rp = (const u32x4*)(pub + (size_t)(2 * I) * NBLK) + lane;
                do { __builtin_amdgcn_s_sleep(1); qB = load_rec_syncx4(rp); }
                while (((qB.x & qB.y & qB.z & qB.w) & 0x10000u) == 0u);
            }
            mAlo = (qA.x & 0xFFFFu) | ((qA.y & 0xFFFFu) << 16);
            mAhi = (qA.z & 0xFFFFu) | ((qA.w & 0xFFFFu) << 16);
            mBlo = (qB.x & 0xFFFFu) | ((qB.y & 0xFFFFu) << 16);
            mBhi = (qB.z & 0xFFFFu) | ((qB.w & 0xFFFFu) << 16);
        }
        // packed count butterfly (nA in lo16, nB in hi16; sums <= 4096)
        unsigned cnt = (unsigned)(__popc(mAlo) + __popc(mAhi))
                     | ((unsigned)(__popc(mBlo) + __popc(mBhi)) << 16);
        cnt += __shfl_xor(cnt, 1);  cnt += __shfl_xor(cnt, 2);
        cnt += __shfl_xor(cnt, 4);  cnt += __shfl_xor(cnt, 8);
        cnt += __shfl_xor(cnt, 16); cnt += __shfl_xor(cnt, 32);

        int in0 = (ip_cur << 16) >> 16;     // in(2I)
        int in1 = ip_cur >> 16;             // in(2I+1)

        // ===== gather: 4 independent chains, straight-line 2x8 slots =====
        unsigned aA0=0,aA1=0,aA2=0,aA3=0,aA4=0,aA5=0,aA6=0,aA7=0;
        unsigned gB0=0,gB1=0,gB2=0,gB3=0,gB4=0,gB5=0,gB6=0,gB7=0;
        {
            unsigned alo = mAlo, ahi = mAhi, blo = mBlo, bhi = mBhi;
#pragma unroll
            for (int grp = 0; grp < 2; ++grp) {
                unsigned beA0=0,boA0=0,beA1=0,boA1=0;
                unsigned beB0=0,boB0=0,beB1=0,boB1=0;
#pragma unroll
                for (int u = 0; u < 8; ++u) {
                    int bA0 = alo ? (int)__builtin_ctz(alo) : bz;
                    int bA1 = ahi ? (int)(32 + __builtin_ctz(ahi)) : bz;
                    int bB0i = blo ? (int)__builtin_ctz(blo) : bz;
                    int bB1i = bhi ? (int)(32 + __builtin_ctz(bhi)) : bz;
                    alo &= alo - 1; ahi &= ahi - 1; blo &= blo - 1; bhi &= bhi - 1;
                    u32x2 wA0 = wl[bA0], wA1 = wl[bA1];
                    u32x2 wB0 = wl[bB0i], wB1 = wl[bB1i];
                    beA0 += wA0.x & M4;  boA0 += (wA0.x >> 4) & M4;
                    beA1 += wA0.y & M4;  boA1 += (wA0.y >> 4) & M4;
                    beA0 += wA1.x & M4;  boA0 += (wA1.x >> 4) & M4;
                    beA1 += wA1.y & M4;  boA1 += (wA1.y >> 4) & M4;
                    beB0 += wB0.x & M4;  boB0 += (wB0.x >> 4) & M4;
                    beB1 += wB0.y & M4;  boB1 += (wB0.y >> 4) & M4;
                    beB0 += wB1.x & M4;  boB0 += (wB1.x >> 4) & M4;
                    beB1 += wB1.y & M4;  boB1 += (wB1.y >> 4) & M4;
                }
                aA0 += beA0 & M8; aA1 += (beA0 >> 8) & M8;
                aA2 += boA0 & M8; aA3 += (boA0 >> 8) & M8;
                aA4 += beA1 & M8; aA5 += (beA1 >> 8) & M8;
                aA6 += boA1 & M8; aA7 += (boA1 >> 8) & M8;
                gB0 += beB0 & M8; gB1 += (beB0 >> 8) & M8;
                gB2 += boB0 & M8; gB3 += (boB0 >> 8) & M8;
                gB4 += beB1 & M8; gB5 += (beB1 >> 8) & M8;
                gB6 += boB1 & M8; gB7 += (boB1 >> 8) & M8;
            }
            while (alo | ahi | blo | bhi) {      // rare: chain popc > 16
                int bA0 = alo ? (int)__builtin_ctz(alo) : bz;
                int bA1 = ahi ? (int)(32 + __builtin_ctz(ahi)) : bz;
                int bB0i = blo ? (int)__builtin_ctz(blo) : bz;
                int bB1i = bhi ? (int)(32 + __builtin_ctz(bhi)) : bz;
                alo &= alo - 1; ahi &= ahi - 1; blo &= blo - 1; bhi &= bhi - 1;
                u32x2 wA0 = wl[bA0], wA1 = wl[bA1];
                u32x2 wB0 = wl[bB0i], wB1 = wl[bB1i];
                unsigned beA0 = (wA0.x & M4) + (wA1.x & M4);
                unsigned boA0 = ((wA0.x >> 4) & M4) + ((wA1.x >> 4) & M4);
                unsigned beA1 = (wA0.y & M4) + (wA1.y & M4);
                unsigned boA1 = ((wA0.y >> 4) & M4) + ((wA1.y >> 4) & M4);
                unsigned beB0 = (wB0.x & M4) + (wB1.x & M4);
                unsigned boB0 = ((wB0.x >> 4) & M4) + ((wB1.x >> 4) & M4);
                unsigned beB1 = (wB0.y & M4) + (wB1.y & M4);
                unsigned boB1 = ((wB0.y >> 4) & M4) + ((wB1.y >> 4) & M4);
                aA0 += beA0 & M8; aA1 += (beA0 >> 8) & M8;
                aA2 += boA0 & M8; aA3 += (boA0 >> 8) & M8;
                aA4 += beA1 & M8; aA5 += (beA1 >> 8) & M8;
                aA6 += boA1 & M8; aA7 += (boA1 >> 8) & M8;
                gB0 += beB0 & M8; gB1 += (beB0 >> 8) & M8;
                gB2 += boB0 & M8; gB3 += (boB0 >> 8) & M8;
                gB4 += beB1 & M8; gB5 += (beB1 >> 8) & M8;
                gB6 += boB1 & M8; gB7 += (boB1 >> 8) & M8;
            }
        }

        // ===== step 5: fb(2I), syn(2I), out(2I+2), publish pub[2I+2] =====
        unsigned gAf;
        BFLY_FIELD(aA0,aA1,aA2,aA3,aA4,aA5,aA6,aA7,gAf);
        int fbA = (int)((gAf >> jsh) & 0xFFFFu) - 8 * (int)(cnt & 0xFFFFu);
        int syn0 = (syn_m1 - (syn_m1 >> 4)) + in0 + fbA;         // syn(2I)
        int mem1 = (mpr1 - (mpr1 >> 3)) + syn0;                  // new_mem(2I+1)
        int mpr2 = out1 ? 0 : mem1;                              // m'(2I+2)
        int out2 = (mpr2 - 1 > 0) ? 1 : 0;                       // out(2I+2)
        unsigned om2 = (unsigned)__ballot(out2) & 0xFFFFu;
        if (lane == 0)
            store_rec4(pub + (size_t)(2 * I + 2) * NBLK + bid, 0x10000u | om2);

        // ===== prefetch rows 2I+1, 2I+2 and next in-pair =====
        __builtin_amdgcn_global_load_lds(
            (const void*)(pub + (size_t)(2 * I + 1) * NBLK + (lane << 2)),
            (void*)&s_recA[cur ^ 1][0], 16, 0, 17);
        __builtin_amdgcn_global_load_lds(
            (const void*)(pub + (size_t)(2 * I + 2) * NBLK + (lane << 2)),
            (void*)&s_recB[cur ^ 1][0], 16, 0, 17);
        int ip_next = ip_base[(I + 1) * 16];

        // ===== rotate state =====
        syn_m2 = syn0; in1_prev = in1; mpr = mpr2; out_c = out2;
        nBred = (int)(cnt >> 16);
        bB0=gB0; bB1=gB1; bB2=gB2; bB3=gB3; bB4=gB4; bB5=gB5; bB6=gB6; bB7=gB7;
        ip_cur = ip_next;
    }
#undef BFLY_FIELD
}

// ---------------------------------------------------------------------------
// ro[t][o] = sum_{k in spikes(t)} w2[o][k]; records: 0x10000|mask16
__global__ __launch_bounds__(256) void k_rocur(
    const int* __restrict__ w2,                // [N_OUT][N_HID]
    const unsigned* __restrict__ pub,
    int* __restrict__ ro)                      // [T][N_OUT]
{
    const int t = blockIdx.x;
    const int tid = threadIdx.x;
    __shared__ unsigned short s_list[N_HID];
    __shared__ int s_red[32][8];
    __shared__ int s_n;
    if (tid < 64) {
        const unsigned* rp = pub + (size_t)t * NBLK + (tid << 2);
        unsigned long long m =
            (unsigned long long)((rp[0] & 0xFFFFu) | ((rp[1] & 0xFFFFu) << 16)) |
            ((unsigned long long)((rp[2] & 0xFFFFu) | ((rp[3] & 0xFFFFu) << 16)) << 32);
        int cnt = __popcll(m);
        int inc = cnt;
#pragma unroll
        for (int d = 1; d < 64; d <<= 1) {
            int v = __shfl_up(inc, d);
            if (tid >= d) inc += v;
        }
        int p = inc - cnt;
        while (m) {
            s_list[p++] = (unsigned short)((tid << 6) | __builtin_ctzll(m));
            m &= m - 1;
        }
        if (tid == 63) s_n = inc;
    }
    __syncthreads();
    const int n = s_n;
    const int o = tid >> 3;
    const int r = tid & 7;
    if (o < N_OUT) {
        int acc = 0;
        for (int jj = r; jj < n; jj += 8) acc += w2[(size_t)o * N_HID + s_list[jj]];
        s_red[o][r] = acc;
    }
    __syncthreads();
    if (tid < N_OUT) {
        int acc = 0;
#pragma unroll
        for (int q = 0; q < 8; ++q) acc += s_red[tid][q];
        ro[(size_t)t * N_OUT + tid] = acc;
    }
}

// ---------------------------------------------------------------------------
// readout LIF scan; LDS-staged reads + coalesced stores. out [N_OUT][T] int32.
#define CH 250
__global__ __launch_bounds__(256) void k_scan(const int* __restrict__ ro,
                                              int* __restrict__ out)
{
    __shared__ int s_ro[CH * N_OUT];
    __shared__ int s_out[CH * N_OUT];
    const int tid = threadIdx.x;
    int rm = 0, rs = 0;
    for (int c = 0; c < T_STEPS / CH; ++c) {
        for (int i = tid; i < CH * N_OUT; i += 256)
            s_ro[i] = ro[c * CH * N_OUT + i];
        __syncthreads();
        if (tid < N_OUT) {
            for (int jj = 0; jj < CH; ++jj) {
                rm = (rm - (rm >> 3)) + rs;
                rs = (rs - (rs >> 4)) + s_ro[jj * N_OUT + tid];
                s_out[jj * N_OUT + tid] = rm;
            }
        }
        __syncthreads();
        for (int i = tid; i < CH * N_OUT; i += 256) {
            int o = i / CH, jj = i - o * CH;
            out[o * T_STEPS + c * CH + jj] = s_out[jj * N_OUT + o];
        }
        __syncthreads();
    }
}

// ---------------------------------------------------------------------------
extern "C" void kernel_launch(void* const* d_in, const int* in_sizes, int n_in,
                              void* d_out, int out_size, void* d_ws, size_t ws_size,
                              hipStream_t stream)
{
    const int* spk = (const int*)d_in[0];   // [1000][700]
    const int* w1  = (const int*)d_in[1];   // [4096][700]
    const int* v1  = (const int*)d_in[2];   // [4096][4096]
    const int* w2  = (const int*)d_in[3];   // [20][4096]
    int* out = (int*)d_out;                 // [20][1000] int32

    char* ws = (char*)d_ws;
    constexpr size_t SZ_PUB    = (size_t)(T_STEPS + 4) * NBLK * 4;  // 1,028,096
    constexpr size_t OFF_PUB   = 0;
    constexpr size_t OFF_INALL = OFF_PUB + SZ_PUB;
    constexpr size_t OFF_V1N   = OFF_INALL + 8192000;
    constexpr size_t OFF_W1T   = OFF_V1N + 8388608;
    constexpr size_t OFF_RO    = OFF_W1T + 2867200;

    unsigned*       pub    = (unsigned*)(ws + OFF_PUB);
    short*          in_all = (short*)(ws + OFF_INALL);
    unsigned char*  v1n    = (unsigned char*)(ws + OFF_V1N);
    signed char*    w1t    = (signed char*)(ws + OFF_W1T);
    int*            ro     = (int*)(ws + OFF_RO);

    hipMemsetAsync(pub, 0, SZ_PUB, stream);   // clear flags (graph replays)

    dim3 tb(32, 8);
    k_prep_v1n<<<dim3(64, 256), 256, 0, stream>>>(v1, v1n);
    k_transpose_i8<<<dim3(22, 128), tb, 0, stream>>>(w1, w1t, N_HID, N_IN, N_HID);
    k_inall<<<dim3(16, 63), 256, 0, stream>>>(w1t, spk, in_all);

    k_main<<<dim3(NBLK), dim3(64), 0, stream>>>(in_all, (const u32x2*)v1n, pub);

    k_rocur<<<dim3(T_STEPS), 256, 0, stream>>>(w2, pub, ro);
    k_scan<<<1, 256, 0, stream>>>(ro, out);
}